// Round 18
// baseline (414.594 us; speedup 1.0000x reference)
//
#include <hip/hip_runtime.h>
#include <math.h>

#define NH 4
#define ND 64
#define NC 128
#define NHD 256
#define NM 30
#define NK 10
#define EPSF 1e-6f
#define RATIO 0.18257418583505536f    // 1/sqrt(30)
#define QKSCALE 0.7071067811865476f   // inv_sqrt_tau(=2) * 64^{-1/4}(=0.353553)
#define NSEG 48                       // kvs2 n-segments
#define NSEG2 128                     // kg_sum partial segments

typedef float f32x4 __attribute__((ext_vector_type(4)));
typedef short s16x8 __attribute__((ext_vector_type(8)));

__device__ __forceinline__ unsigned f2ord(float f){ unsigned b=__float_as_uint(f); return (b&0x80000000u)?~b:(b|0x80000000u); }
__device__ __forceinline__ float ord2f(unsigned u){ return __uint_as_float((u&0x80000000u)?(u&0x7fffffffu):~u); }
__device__ __forceinline__ ushort f2bf(float f){ unsigned b=__float_as_uint(f); return (ushort)((b + 0x7fffu + ((b>>16)&1u))>>16); }
__device__ __forceinline__ float bf2f(ushort u){ return __uint_as_float(((unsigned)u)<<16); }
__device__ __forceinline__ void bfsplit(float p, unsigned& hi, unsigned& lo){
    unsigned pb = __float_as_uint(p);
    unsigned t  = pb + 0x8000u;
    unsigned hf = t & 0xffff0000u;
    hi = t >> 16;
    lo = __float_as_uint(p - __uint_as_float(hf)) >> 16;
}

// ---------------------------------------------------------------------------
// K-prep (merged): [0,48) W panel; [48,64) dd-folded panel; [64,64+zb) zero-
// fill + init; [.., +egb) egT fill.
// ---------------------------------------------------------------------------
__global__ __launch_bounds__(256) void k_prep(const float* __restrict__ Wq,
    const float* __restrict__ Wk, const float* __restrict__ Wv,
    const float* __restrict__ proj, const float* __restrict__ bq,
    const float* __restrict__ bk, ushort* __restrict__ Wt_h,
    ushort* __restrict__ Wt_l, float* __restrict__ bd, float* __restrict__ kpT,
    ushort* __restrict__ vT16, unsigned* __restrict__ mxk_u,
    const float* __restrict__ gum, float* __restrict__ egT,
    int zwork, int zb, int N, int Npad)
{
    __shared__ float wd[16*129];
    int b = blockIdx.x;
    int tid = threadIdx.x;
    if (b < 48){
        int idx = b*256 + tid;
        int lane = idx & 63, ks = (idx>>6)&3, tile = idx>>8;
        int c = tile*16 + (lane&15);
        int k0 = ks*32 + (lane>>4)*8;
        const float* W; int cc;
        if (c < 256)      { W = Wq; cc = c; }
        else if (c < 512) { W = Wk; cc = c-256; }
        else              { W = Wv; cc = c-512; }
        #pragma unroll
        for (int j=0;j<8;j++){
            float w = W[(size_t)(k0+j)*NHD + cc];
            ushort h = f2bf(w);
            Wt_h[(size_t)idx*8+j] = h;
            Wt_l[(size_t)idx*8+j] = f2bf(w - bf2f(h));
        }
    } else if (b < 64){
        int dt = b - 48;
        int cl = tid & 15, rc = tid >> 4;
        int cd = dt*16 + cl;
        int isq = (cd < 128);
        int hm = cd & 127;
        int valid = (hm < 120);
        int hh = valid ? hm/30 : 0, m = valid ? hm%30 : 0;
        const float* W = isq ? Wq : Wk;
        const float* prow = proj + (size_t)m*ND;
        #pragma unroll
        for (int rr=0; rr<8; rr++){
            int row = rc*8 + rr;
            float s = 0.f;
            if (valid){
                const float* wr = W + (size_t)row*NHD + hh*64;
                for (int d=0; d<64; d++) s = fmaf(wr[d], prow[d], s);
                s *= QKSCALE;
            }
            wd[cl*129 + row] = s;
        }
        if (tid < 16){
            int cd2 = dt*16 + tid;
            int hm2 = cd2 & 127;
            float s = 0.f;
            if (hm2 < 120){
                int hh2 = hm2/30, m2 = hm2%30;
                const float* bvec = (cd2 < 128) ? bq : bk;
                const float* pr2 = proj + (size_t)m2*ND;
                for (int d=0; d<64; d++) s = fmaf(bvec[hh2*64+d], pr2[d], s);
                s *= QKSCALE;
            }
            bd[cd2] = s;
        }
        __syncthreads();
        int ks = tid >> 6, lane = tid & 63;
        int colL = lane & 15, k0 = ks*32 + (lane>>4)*8;
        unsigned hi[8], lo[8];
        #pragma unroll
        for (int j=0;j<8;j++){
            float v = wd[colL*129 + k0 + j];
            bfsplit(v, hi[j], lo[j]);
        }
        uint4 ph, pl;
        ph.x=hi[0]|(hi[1]<<16); ph.y=hi[2]|(hi[3]<<16); ph.z=hi[4]|(hi[5]<<16); ph.w=hi[6]|(hi[7]<<16);
        pl.x=lo[0]|(lo[1]<<16); pl.y=lo[2]|(lo[3]<<16); pl.z=lo[4]|(lo[5]<<16); pl.w=lo[6]|(lo[7]<<16);
        size_t off = ((size_t)(48+dt)*4 + ks)*64 + lane;
        ((uint4*)Wt_h)[off] = ph;
        ((uint4*)Wt_l)[off] = pl;
    } else if (b < 64 + zb){
        int idx = (b-64)*256 + tid;
        int tail = Npad - N;
        int w1 = 8*Npad, w2 = 128*tail, w3 = 256*tail;
        if (idx < w1){
            int r = idx / Npad, c = idx % Npad;
            int hh = r>>1, m = 30 + (r&1);
            kpT[((size_t)(hh*32+m))*Npad + c] = 0.f;
        } else if (idx < w1+w2){
            int j = idx - w1; int r = j / tail, c = N + j % tail;
            kpT[(size_t)r*Npad + c] = 0.f;
        } else if (idx < w1+w2+w3){
            int j = idx - w1 - w2; int r = j / tail, c = N + j % tail;
            vT16[(size_t)r*Npad + c] = 0;
        } else if (idx >= zwork && idx < zwork + 4){
            mxk_u[idx - zwork] = 0u;
        }
    } else {
        int n0 = (b - 64 - zb)*64;
        for (int i = tid; i < 64*40; i += 256){
            int nl = i / 40, hk = i % 40;
            int n = n0 + nl;
            if (n >= Npad) continue;
            float v = (n < N) ? __expf(gum[(size_t)n*40 + hk]) : 0.f;
            egT[(size_t)hk*Npad + n] = v;
        }
    }
}

// ---------------------------------------------------------------------------
// K1: single MFMA pass over 64 col-tiles (q|k|v|dd).  FROZEN (120us, 84 VGPR).
// ---------------------------------------------------------------------------
__global__ __launch_bounds__(256) void k_qkv(
    const float* __restrict__ z,
    const ushort* __restrict__ Wt_h, const ushort* __restrict__ Wt_l,
    const float* __restrict__ bq, const float* __restrict__ bk,
    const float* __restrict__ bv, const float* __restrict__ bd,
    float* __restrict__ qp, ushort* __restrict__ qpe,
    float* __restrict__ dd_k, float* __restrict__ diag_k,
    ushort* __restrict__ vT16, int N, int Npad)
{
    __shared__ float pq[32*132];
    __shared__ float diagq[32*4];
    __shared__ float mxs[32*4];
    int tid = threadIdx.x;
    int n0 = blockIdx.x * 32;
    int w = tid >> 6, lane = tid & 63;
    int l15 = lane & 15, kgrp = lane >> 4;

    s16x8 ah[2][4], al[2][4];
    #pragma unroll
    for (int g=0; g<2; g++){
        int nn = n0 + g*16 + l15; if (nn > N-1) nn = N-1;
        const float* zrow = z + (size_t)nn*NC;
        #pragma unroll
        for (int ks=0;ks<4;ks++){
            f32x4 f0 = *(const f32x4*)(zrow + ks*32 + kgrp*8);
            f32x4 f1 = *(const f32x4*)(zrow + ks*32 + kgrp*8 + 4);
            #pragma unroll
            for (int j=0;j<4;j++){
                float v0 = f0[j]; ushort h0 = f2bf(v0);
                ah[g][ks][j]   = (short)h0; al[g][ks][j]   = (short)f2bf(v0 - bf2f(h0));
                float v1 = f1[j]; ushort h1 = f2bf(v1);
                ah[g][ks][4+j] = (short)h1; al[g][ks][4+j] = (short)f2bf(v1 - bf2f(h1));
            }
        }
    }

    float sq0[4] = {0.f,0.f,0.f,0.f}, sq1[4] = {0.f,0.f,0.f,0.f};
    const uint4* WH = (const uint4*)Wt_h;
    const uint4* WL = (const uint4*)Wt_l;

    for (int nt=0; nt<16; nt++){
        int tile = w*16 + nt;
        f32x4 acc0 = {0.f,0.f,0.f,0.f}, acc1 = {0.f,0.f,0.f,0.f};
        #pragma unroll
        for (int ks=0;ks<4;ks++){
            uint4 bhu = WH[(size_t)(tile*4+ks)*64 + lane];
            uint4 blu = WL[(size_t)(tile*4+ks)*64 + lane];
            s16x8 bh = __builtin_bit_cast(s16x8, bhu);
            s16x8 bl = __builtin_bit_cast(s16x8, blu);
            acc0 = __builtin_amdgcn_mfma_f32_16x16x32_bf16(ah[0][ks], bl, acc0, 0,0,0);
            acc0 = __builtin_amdgcn_mfma_f32_16x16x32_bf16(al[0][ks], bh, acc0, 0,0,0);
            acc0 = __builtin_amdgcn_mfma_f32_16x16x32_bf16(ah[0][ks], bh, acc0, 0,0,0);
            acc1 = __builtin_amdgcn_mfma_f32_16x16x32_bf16(ah[1][ks], bl, acc1, 0,0,0);
            acc1 = __builtin_amdgcn_mfma_f32_16x16x32_bf16(al[1][ks], bh, acc1, 0,0,0);
            acc1 = __builtin_amdgcn_mfma_f32_16x16x32_bf16(ah[1][ks], bh, acc1, 0,0,0);
        }
        int c = tile*16 + l15;
        if (c < 512){
            int ccc = c & 255;
            float bias = (c < 256) ? bq[ccc] : bk[ccc];
            #pragma unroll
            for (int i=0;i<4;i++){
                float x0 = (acc0[i]+bias)*QKSCALE; sq0[i] = fmaf(x0,x0,sq0[i]);
                float x1 = (acc1[i]+bias)*QKSCALE; sq1[i] = fmaf(x1,x1,sq1[i]);
            }
            if ((nt&3)==3){
                int hh = nt>>2;
                #pragma unroll
                for (int i=0;i<4;i++){
                    float s0 = sq0[i], s1 = sq1[i];
                    s0 += __shfl_xor(s0,1); s0 += __shfl_xor(s0,2);
                    s0 += __shfl_xor(s0,4); s0 += __shfl_xor(s0,8);
                    s1 += __shfl_xor(s1,1); s1 += __shfl_xor(s1,2);
                    s1 += __shfl_xor(s1,4); s1 += __shfl_xor(s1,8);
                    if (l15==0){
                        int nd0 = kgrp*4+i, nd1 = 16+kgrp*4+i;
                        if (w==0){ diagq[nd0*4+hh] = 0.5f*s0; diagq[nd1*4+hh] = 0.5f*s1; }
                        else {
                            int na = n0+nd0, nb2 = n0+nd1;
                            if (na < N) diag_k[(size_t)na*4+hh] = 0.5f*s0;
                            if (nb2 < N) diag_k[(size_t)nb2*4+hh] = 0.5f*s1;
                        }
                    }
                    sq0[i]=0.f; sq1[i]=0.f;
                }
            }
        } else if (c < 768){
            int cv = c - 512;
            float bias = bv[cv];
            {
                ushort t0=f2bf(acc0[0]+bias), t1=f2bf(acc0[1]+bias);
                ushort t2=f2bf(acc0[2]+bias), t3=f2bf(acc0[3]+bias);
                int nb = n0 + kgrp*4;
                ushort* dst = &vT16[(size_t)cv*Npad + nb];
                if (nb+4 <= N){ uint2 pk; pk.x=(unsigned)t0|((unsigned)t1<<16); pk.y=(unsigned)t2|((unsigned)t3<<16); *(uint2*)dst=pk; }
                else { if(nb<N)dst[0]=t0; if(nb+1<N)dst[1]=t1; if(nb+2<N)dst[2]=t2; if(nb+3<N)dst[3]=t3; }
            }
            {
                ushort t0=f2bf(acc1[0]+bias), t1=f2bf(acc1[1]+bias);
                ushort t2=f2bf(acc1[2]+bias), t3=f2bf(acc1[3]+bias);
                int nb = n0 + 16 + kgrp*4;
                ushort* dst = &vT16[(size_t)cv*Npad + nb];
                if (nb+4 <= N){ uint2 pk; pk.x=(unsigned)t0|((unsigned)t1<<16); pk.y=(unsigned)t2|((unsigned)t3<<16); *(uint2*)dst=pk; }
                else { if(nb<N)dst[0]=t0; if(nb+1<N)dst[1]=t1; if(nb+2<N)dst[2]=t2; if(nb+3<N)dst[3]=t3; }
            }
        } else {
            int cd = c - 768;
            float bias = bd[cd];
            if (cd < 128){
                #pragma unroll
                for (int i=0;i<4;i++){
                    pq[(kgrp*4+i)*132 + cd]      = acc0[i]+bias;
                    pq[(16+kgrp*4+i)*132 + cd]   = acc1[i]+bias;
                }
            } else {
                int hm = cd - 128;
                if (hm < 120){
                    int hh = hm/30, m = hm%30;
                    size_t base = (size_t)hh*N*NM;
                    #pragma unroll
                    for (int i=0;i<4;i++){
                        int na = n0+kgrp*4+i, nb2 = n0+16+kgrp*4+i;
                        if (na < N)  dd_k[base + (size_t)na*NM + m]  = acc0[i]+bias;
                        if (nb2 < N) dd_k[base + (size_t)nb2*NM + m] = acc1[i]+bias;
                    }
                }
            }
        }
    }
    __syncthreads();

    if (tid < 128){
        int node = tid>>2, hh = tid&3;
        const float* pr = &pq[node*132 + hh*30];
        float mx = -3.0e38f;
        #pragma unroll
        for (int m=0;m<NM;m++) mx = fmaxf(mx, pr[m]);
        mxs[tid] = mx;
    }
    __syncthreads();

    for (int idx = tid; idx < 32*120; idx += 256){
        int node = idx/120, hm = idx%120;
        int n = n0 + node;
        if (n >= N) continue;
        int hh = hm/30;
        float val = RATIO * (__expf(pq[node*132+hm] - diagq[node*4+hh] - mxs[node*4+hh]) + EPSF);
        qp[(size_t)n*120 + hm] = val;
        qpe[(size_t)n*128 + hm] = f2bf(val);
    }
}

// ---------------------------------------------------------------------------
// K1.5: global max of dd_k per head — 32KB chunk/block, float4, 4 chains.
// ---------------------------------------------------------------------------
__global__ __launch_bounds__(256) void k_maxred(const float* __restrict__ dd_k,
                                                unsigned* __restrict__ mxk_u, int N)
{
    const int CH = 8192;
    int hh = blockIdx.y;
    size_t len = (size_t)N*NM;
    size_t base = (size_t)hh*len;
    size_t lo = (size_t)blockIdx.x*CH;
    size_t hi = lo + CH; if (hi > len) hi = len;
    float m0=-3.0e38f, m1=-3.0e38f, m2=-3.0e38f, m3=-3.0e38f;
    size_t j = lo + (size_t)threadIdx.x*4;
    for (; j + 4 <= hi; j += 1024){
        float4 v = *(const float4*)(dd_k + base + j);
        m0 = fmaxf(m0, v.x); m1 = fmaxf(m1, v.y);
        m2 = fmaxf(m2, v.z); m3 = fmaxf(m3, v.w);
    }
    if (j < hi){
        for (size_t t = j; t < hi; ++t) m0 = fmaxf(m0, dd_k[base + t]);
    }
    float mx = fmaxf(fmaxf(m0, m1), fmaxf(m2, m3));
    for (int o=32;o>0;o>>=1) mx = fmaxf(mx, __shfl_down(mx, o));
    __shared__ float wmax[4];
    if ((threadIdx.x & 63) == 0) wmax[threadIdx.x >> 6] = mx;
    __syncthreads();
    if (threadIdx.x == 0){
        mx = fmaxf(fmaxf(wmax[0],wmax[1]), fmaxf(wmax[2],wmax[3]));
        atomicMax(&mxk_u[hh], f2ord(mx));
    }
}

// ---------------------------------------------------------------------------
// K2: kp features.  64 nodes/block; kpT writes coalesced via LDS transpose.
// ---------------------------------------------------------------------------
__global__ __launch_bounds__(256) void k_kp(const float* __restrict__ dd_k,
    const float* __restrict__ diag_k, const unsigned* __restrict__ mxk_u,
    ushort* __restrict__ kpe, float* __restrict__ kpT,
    float* __restrict__ kp_part, int N, int Npad)
{
    __shared__ float tbuf[120*67];
    __shared__ float psum[120];
    int tid = threadIdx.x;
    if (tid < 120) psum[tid] = 0.f;
    float mxk[NH];
    #pragma unroll
    for (int hh=0;hh<NH;hh++) mxk[hh] = ord2f(mxk_u[hh]);
    __syncthreads();
    int n0 = blockIdx.x * 64;
    for (int r = 0; r < 30; r++) {
        int idx = r*256 + tid;
        int nl = idx / 120, hm = idx % 120;
        int n = n0 + nl;
        float val = 0.f;
        if (n < N){
            int hh = hm/30, m = hm%30;
            val = RATIO * (__expf(dd_k[(size_t)hh*N*NM + (size_t)n*NM + m]
                                  - diag_k[(size_t)n*4+hh] - mxk[hh]) + EPSF);
            kpe[(size_t)n*128 + hm] = f2bf(val);
            atomicAdd(&psum[hm], val);
        }
        tbuf[hm*67 + nl] = val;
    }
    __syncthreads();
    for (int i = tid; i < 120*64; i += 256){
        int row = i>>6, cc = i&63;
        int hh = row/30, m = row%30;
        kpT[(size_t)(hh*32+m)*Npad + n0 + cc] = tbuf[row*67 + cc];
    }
    if (tid < 120) kp_part[blockIdx.x*120 + tid] = psum[tid];
}

// ---------------------------------------------------------------------------
// K-mid: kp_sum column reduce (120 blocks).
// ---------------------------------------------------------------------------
__global__ __launch_bounds__(256) void k_mid(const float* __restrict__ kp_part,
    float* __restrict__ kp_sum, int nblk)
{
    __shared__ float ws_[4];
    int b = blockIdx.x;
    int tid = threadIdx.x;
    float s = 0.f;
    for (int bb = tid; bb < nblk; bb += 256) s += kp_part[(size_t)bb*120 + b];
    for (int o=32;o>0;o>>=1) s += __shfl_down(s, o);
    if ((tid & 63) == 0) ws_[tid>>6] = s;
    __syncthreads();
    if (tid == 0) kp_sum[b] = ws_[0]+ws_[1]+ws_[2]+ws_[3];
}

// ---------------------------------------------------------------------------
// K-mega1 (fused): [0,192) kvs2 MFMA partials; [192,704) kg partials;
// [704,704+denb) den -> qpe tails.
// ---------------------------------------------------------------------------
__global__ __launch_bounds__(256,1) void k_mega1(const float* __restrict__ kpT,
    const float* __restrict__ egT, const ushort* __restrict__ vT16,
    float* __restrict__ part, float* __restrict__ kg_part,
    const float* __restrict__ qp, const float* __restrict__ kp_sum,
    ushort* __restrict__ qpe, int N, int Npad)
{
    __shared__ float kps_s[120];
    int b = blockIdx.x;
    int tid = threadIdx.x;
    if (b < 192){
        int seg = b % NSEG, hh = b / NSEG;
        int w = tid >> 6, lane = tid & 63;
        int l15 = lane & 15, lg = lane >> 4;
        int steps_total = Npad/32;
        int per = (steps_total + NSEG-1)/NSEG;
        int s0 = seg*per, s1 = min(steps_total, s0+per);

        const ushort* vbase = vT16 + (size_t)hh*64*Npad;
        const float* kpbase = kpT + (size_t)hh*32*Npad;
        const float* egbase = egT + (size_t)hh*10*Npad;

        f32x4 acc[5][4];
        #pragma unroll
        for (int mt=0;mt<5;mt++)
            #pragma unroll
            for (int nt=0;nt<4;nt++) acc[mt][nt] = (f32x4){0.f,0.f,0.f,0.f};

        for (int st = s0; st < s1; ++st){
            int n0 = st*32 + lg*8;
            s16x8 bf[4];
            #pragma unroll
            for (int nt=0;nt<4;nt++){
                uint4 u = *(const uint4*)(vbase + (size_t)(nt*16 + l15)*Npad + n0);
                bf[nt] = __builtin_bit_cast(s16x8, u);
            }
            #pragma unroll
            for (int mt=0;mt<5;mt++){
                int r = w*80 + mt*16 + l15;
                int m = r & 31, kk = r >> 5;
                const float* kprow = kpbase + (size_t)m*Npad;
                const float* egrow = egbase + (size_t)kk*Npad;
                f32x4 kp0 = *(const f32x4*)(kprow + n0);
                f32x4 kp1 = *(const f32x4*)(kprow + n0 + 4);
                f32x4 eg0 = *(const f32x4*)(egrow + n0);
                f32x4 eg1 = *(const f32x4*)(egrow + n0 + 4);
                f32x4 pr0 = kp0*eg0, pr1 = kp1*eg1;
                unsigned hi[8], lo[8];
                #pragma unroll
                for (int j=0;j<4;j++){
                    bfsplit(pr0[j], hi[j], lo[j]);
                    bfsplit(pr1[j], hi[4+j], lo[4+j]);
                }
                uint4 ahu, alu;
                ahu.x = hi[0]|(hi[1]<<16); ahu.y = hi[2]|(hi[3]<<16);
                ahu.z = hi[4]|(hi[5]<<16); ahu.w = hi[6]|(hi[7]<<16);
                alu.x = lo[0]|(lo[1]<<16); alu.y = lo[2]|(lo[3]<<16);
                alu.z = lo[4]|(lo[5]<<16); alu.w = lo[6]|(lo[7]<<16);
                s16x8 ah = __builtin_bit_cast(s16x8, ahu);
                s16x8 al = __builtin_bit_cast(s16x8, alu);
                #pragma unroll
                for (int nt=0;nt<4;nt++){
                    acc[mt][nt] = __builtin_amdgcn_mfma_f32_16x16x32_bf16(al, bf[nt], acc[mt][nt], 0,0,0);
                    acc[mt][nt] = __builtin_amdgcn_mfma_f32_16x16x32_bf16(ah, bf[nt], acc[mt][nt], 0,0,0);
                }
            }
        }
        float* dst = part + ((size_t)hh*NSEG + seg)*20480;
        #pragma unroll
        for (int mt=0;mt<5;mt++)
            #pragma unroll
            for (int nt=0;nt<4;nt++)
                #pragma unroll
                for (int i=0;i<4;i++){
                    int rr = w*80 + mt*16 + lg*4 + i;
                    dst[rr*64 + nt*16 + l15] = acc[mt][nt][i];
                }
    } else if (b < 704){
        int idx = b - 192;
        int s2 = idx & (NSEG2-1), hh = idx >> 7;
        int len = Npad / NSEG2;
        int n0 = s2*len;
        for (int t = tid; t < 320; t += 256){
            int kk = t >> 5, m = t & 31;
            float acc = 0.f;
            if (kk < NK && m < NM){
                const f32x4* kr = (const f32x4*)(kpT + ((size_t)(hh*32+m))*Npad + n0);
                const f32x4* er = (const f32x4*)(egT + ((size_t)(hh*10+kk))*Npad + n0);
                for (int i=0;i<len/4;i++){
                    f32x4 a = kr[i], bb = er[i];
                    acc = fmaf(a.x, bb.x, acc); acc = fmaf(a.y, bb.y, acc);
                    acc = fmaf(a.z, bb.z, acc); acc = fmaf(a.w, bb.w, acc);
                }
            }
            kg_part[((size_t)hh*NSEG2 + s2)*320 + t] = acc;
        }
    } else {
        int n0 = (b - 704)*64;
        for (int i=tid;i<120;i+=256) kps_s[i] = kp_sum[i];
        __syncthreads();
        int nl = tid >> 2, h = tid & 3;
        int n = n0 + nl;
        if (n < N){
            const float* qrow = qp + (size_t)n*120 + h*30;
            float p = 0.f;
            #pragma unroll
            for (int m=0;m<30;m++) p = fmaf(qrow[m], kps_s[h*30+m], p);
            ((float*)qpe)[(size_t)n*64 + 60 + h] = p;
        }
    }
}

// ---------------------------------------------------------------------------
// K-red: [0,300) kvs partial reduce; [300,305) kg reduce.
// ---------------------------------------------------------------------------
__global__ __launch_bounds__(256) void k_red(const float* __restrict__ part,
    float* __restrict__ kvs, const float* __restrict__ kg_part,
    float* __restrict__ kg_sum)
{
    int b = blockIdx.x, tid = threadIdx.x;
    if (b < 300){
        int o = b*256 + tid;
        if (o >= 76800) return;
        int hh = o / 19200, r = o % 19200;
        int km = r >> 6, d = r & 63;
        int kk = km / 30, m = km % 30;
        size_t base = (size_t)hh*NSEG*20480 + (size_t)(kk*32+m)*64 + d;
        float s = 0.f;
        for (int sg=0; sg<NSEG; sg++) s += part[base + (size_t)sg*20480];
        kvs[o] = s;
    } else {
        int o = (b-300)*256 + tid;
        if (o >= 1200) return;
        int hh = o / 300, r = o % 300;
        int kk = r / 30, m = r % 30;
        float s = 0.f;
        for (int i=0;i<NSEG2;i++) s += kg_part[((size_t)hh*NSEG2 + i)*320 + kk*32 + m];
        kg_sum[o] = s;
    }
}

// ---------------------------------------------------------------------------
// K4: WK panels = kvs @ Wo folded, in MFMA B-frag layout, bf16 hi/lo.
// ---------------------------------------------------------------------------
__global__ __launch_bounds__(256) void k_wkprep(const float* __restrict__ kvs,
    const float* __restrict__ Wo, ushort* __restrict__ WKf_h, ushort* __restrict__ WKf_l)
{
    __shared__ float kv_s[30*65];
    __shared__ float wo_s[64*64];
    __shared__ float wks[32*64];
    int ks = blockIdx.x;
    int h = ks/10, kq = ks%10;
    int tid = threadIdx.x;
    for (int i=tid;i<1920;i+=256){ int m=i>>6, d=i&63; kv_s[m*65+d] = kvs[(size_t)h*19200 + (size_t)(kq*30)*64 + i]; }
    for (int i=tid;i<4096;i+=256) wo_s[i] = Wo[(size_t)h*64*64 + i];
    __syncthreads();
    int m = tid>>3, c0 = (tid&7)*8;
    float acc[8] = {0,0,0,0,0,0,0,0};
    if (m < 30){
        for (int d=0; d<64; d++){
            float kv = kv_s[m*65+d];
            const float* wr = &wo_s[d*64 + c0];
            #pragma unroll
            for (int j=0;j<8;j++) acc[j] = fmaf(kv, wr[j], acc[j]);
        }
    }
    #pragma unroll
    for (int j=0;j<8;j++) wks[m*64 + c0 + j] = acc[j];
    __syncthreads();
    int nt = tid>>6, lane = tid&63, l15 = lane&15, lg = lane>>4;
    unsigned hi[8], lo[8];
    #pragma unroll
    for (int jj=0;jj<8;jj++){
        float v = wks[(lg*8+jj)*64 + nt*16 + l15];
        bfsplit(v, hi[jj], lo[jj]);
    }
    uint4 ph, pl;
    ph.x = hi[0]|(hi[1]<<16); ph.y = hi[2]|(hi[3]<<16); ph.z = hi[4]|(hi[5]<<16); ph.w = hi[6]|(hi[7]<<16);
    pl.x = lo[0]|(lo[1]<<16); pl.y = lo[2]|(lo[3]<<16); pl.z = lo[4]|(lo[5]<<16); pl.w = lo[6]|(lo[7]<<16);
    size_t off = ((size_t)ks*4 + nt)*64 + lane;
    ((uint4*)WKf_h)[off] = ph;
    ((uint4*)WKf_l)[off] = pl;
}

// ---------------------------------------------------------------------------
// K-zoedge (fused, STRIPED): zo blocks interleaved 1-in-`stride` among edge
// blocks so MFMA-bound zo overlaps the latency-bound edge gather throughout.
// Bijective mapping: b%stride==0 && b/stride<zoB -> zo(b/stride);
// else edge index = (b/stride<zoB) ? b - b/stride - 1 : b - zoB.
// ---------------------------------------------------------------------------
__global__ __launch_bounds__(256) void k_zoedge(const float* __restrict__ qp,
    const ushort* __restrict__ WKf_h, const ushort* __restrict__ WKf_l,
    const float* __restrict__ kg_sum, const float* __restrict__ Wob,
    const ushort* __restrict__ qpe, const ushort* __restrict__ kpe,
    const int* __restrict__ ei, float* __restrict__ out, float* __restrict__ A,
    int zoB, int stride, int N, int E)
{
    __shared__ float kg_s[1200];
    __shared__ uint4 bs[2][2][256];
    int tid = threadIdx.x;
    int b = blockIdx.x;
    int q = b / stride, r = b % stride;
    bool isZo = (r == 0 && q < zoB);
    if (isZo){
        int w = tid>>6, lane = tid&63, l15 = lane&15, lg = lane>>4;
        int n0 = q*64;
        int n = n0 + w*16 + l15;
        bool nv = (n < N);
        int nc = nv ? n : (N-1);

        for (int i=tid;i<1200;i+=256) kg_s[i] = kg_sum[i];
        {
            const uint4* sH = (const uint4*)WKf_h;
            const uint4* sL = (const uint4*)WKf_l;
            bs[0][0][tid] = sH[tid];
            bs[0][1][tid] = sL[tid];
        }

        float qA[4][8];
        const float* qrow = qp + (size_t)nc*120;
        #pragma unroll
        for (int h=0;h<4;h++)
          #pragma unroll
          for (int jj=0;jj<8;jj++){
            int m = lg*8+jj;
            qA[h][jj] = (m<30) ? qrow[h*30+m] : 0.f;
          }
        __syncthreads();

        f32x4 acc[4];
        #pragma unroll
        for (int nt=0;nt<4;nt++) acc[nt] = (f32x4){0.f,0.f,0.f,0.f};

        #pragma unroll
        for (int h=0;h<4;h++){
          for (int kq=0;kq<10;kq++){
            int ks = h*10+kq;
            int buf = ks&1;
            if (ks < 39){
                const uint4* sH = (const uint4*)WKf_h + (size_t)(ks+1)*256;
                const uint4* sL = (const uint4*)WKf_l + (size_t)(ks+1)*256;
                bs[buf^1][0][tid] = sH[tid];
                bs[buf^1][1][tid] = sL[tid];
            }
            float p = 0.f;
            #pragma unroll
            for (int jj=0;jj<8;jj++){
              int m = lg*8+jj;
              if (m<30) p = fmaf(qA[h][jj], kg_s[h*300 + kq*30 + m], p);
            }
            p += __shfl_xor(p,16);
            p += __shfl_xor(p,32);
            float sc = 0.1f / p;
            unsigned hi[8], lo[8];
            #pragma unroll
            for (int jj=0;jj<8;jj++) bfsplit(qA[h][jj]*sc, hi[jj], lo[jj]);
            uint4 ahu, alu;
            ahu.x = hi[0]|(hi[1]<<16); ahu.y = hi[2]|(hi[3]<<16);
            ahu.z = hi[4]|(hi[5]<<16); ahu.w = hi[6]|(hi[7]<<16);
            alu.x = lo[0]|(lo[1]<<16); alu.y = lo[2]|(lo[3]<<16);
            alu.z = lo[4]|(lo[5]<<16); alu.w = lo[6]|(lo[7]<<16);
            s16x8 ah = __builtin_bit_cast(s16x8, ahu);
            s16x8 al = __builtin_bit_cast(s16x8, alu);
            #pragma unroll
            for (int nt=0;nt<4;nt++){
                s16x8 bh = __builtin_bit_cast(s16x8, bs[buf][0][nt*64+lane]);
                s16x8 bl = __builtin_bit_cast(s16x8, bs[buf][1][nt*64+lane]);
                acc[nt] = __builtin_amdgcn_mfma_f32_16x16x32_bf16(ah, bl, acc[nt], 0,0,0);
                acc[nt] = __builtin_amdgcn_mfma_f32_16x16x32_bf16(al, bh, acc[nt], 0,0,0);
                acc[nt] = __builtin_amdgcn_mfma_f32_16x16x32_bf16(ah, bh, acc[nt], 0,0,0);
            }
            __syncthreads();
          }
        }

        #pragma unroll
        for (int nt=0;nt<4;nt++){
            float bias = Wob[nt*16 + l15];
            #pragma unroll
            for (int i=0;i<4;i++){
                int node = n0 + w*16 + lg*4 + i;
                if (node < N) out[(size_t)node*64 + nt*16 + l15] = acc[nt][i] + bias;
            }
        }
    } else {
        int eb = (q < zoB) ? (b - q - 1) : (b - zoB);
        int e = eb*64 + (tid>>2);
        int sub = tid & 3;
        if (e >= E) return;
        int s = ei[e], t = ei[(size_t)E + e];
        float dnv = ((const float*)(qpe + (size_t)t*128))[60 + sub];
        const uint4* rq = (const uint4*)(qpe + (size_t)t*128) + sub*4;
        const uint4* rk = (const uint4*)(kpe + (size_t)s*128) + sub*4;
        float numA = 0.f, numB = 0.f;
        int bndw = 15 - sub;
        #define PROC(au,bu,wi) { \
            float a0=__uint_as_float((au)<<16),        b0=__uint_as_float((bu)<<16); \
            float a1=__uint_as_float((au)&0xffff0000u),b1=__uint_as_float((bu)&0xffff0000u); \
            float p = fmaf(a0,b0, a1*b1); \
            if ((wi) < bndw) numA += p; else if (sub < 3) numB += p; }
        #pragma unroll
        for (int j=0;j<4;j++){
            uint4 a = rq[j], bb = rk[j];
            PROC(a.x, bb.x, j*4+0)
            PROC(a.y, bb.y, j*4+1)
            PROC(a.z, bb.z, j*4+2)
            PROC(a.w, bb.w, j*4+3)
        }
        #undef PROC
        int lane = tid & 63;
        float nbIn = __shfl(numB, (lane > 0) ? (lane-1) : 0);
        float num = numA + ((sub > 0) ? nbIn : 0.f);
        A[(size_t)e*4 + sub] = num / dnv;
    }
}

// ---------------------------------------------------------------------------
extern "C" void kernel_launch(void* const* d_in, const int* in_sizes, int n_in,
                              void* d_out, int out_size, void* d_ws, size_t ws_size,
                              hipStream_t stream)
{
    const float* z    = (const float*)d_in[0];
    const int*   ei   = (const int*)d_in[1];
    const float* gum  = (const float*)d_in[2];
    const float* proj = (const float*)d_in[3];
    const float* Wq   = (const float*)d_in[4];
    const float* bq   = (const float*)d_in[5];
    const float* Wk   = (const float*)d_in[6];
    const float* bk   = (const float*)d_in[7];
    const float* Wv   = (const float*)d_in[8];
    const float* bv   = (const float*)d_in[9];
    const float* Wo   = (const float*)d_in[10];
    const float* Wob  = (const float*)d_in[11];
    int N = in_sizes[0] / NC;
    int E = in_sizes[1] / 2;
    int Npad = (N + 511) & ~511;

    float* ws = (float*)d_ws;
    size_t o = 0;
    #define ALIGN64 o = (o + 63) & ~(size_t)63;
    float* qp       = ws + o; o += (size_t)N*120;
    ALIGN64
    float* vbuf     = ws + o; o += (size_t)N*NHD;
    ALIGN64
    float* dd_k     = ws + o; o += (size_t)NH*N*NM;      // kvs_part aliases (after kp)
    float* kvs_part = dd_k;
    ALIGN64
    float* egT      = ws + o; o += (size_t)40*Npad;
    ALIGN64
    float* diag_k   = ws + o; o += (size_t)N*4;
    unsigned* mxk_u = (unsigned*)(ws + o); o += 4;
    ALIGN64
    int nkb = (N+63)/64;
    float* kp_part  = ws + o; o += (size_t)nkb*120;
    float* kp_sum   = ws + o; o += 120;
    ALIGN64
    float* kg_part  = ws + o; o += (size_t)NH*NSEG2*320;
    float* kvs      = ws + o; o += 76800;
    float* kg_sum   = ws + o; o += 1200;
    ALIGN64
    ushort* qpe     = (ushort*)(ws + o); o += (size_t)N*64;
    ALIGN64
    ushort* kpe     = (ushort*)(ws + o); o += (size_t)N*64;
    ALIGN64
    ushort* Wt_h    = (ushort*)(ws + o); o += 64*4*64*8/2;
    ALIGN64
    ushort* Wt_l    = (ushort*)(ws + o); o += 64*4*64*8/2;
    ALIGN64
    float* bd       = ws + o; o += 256;
    ALIGN64
    float* kpT      = ws + o; o += (size_t)128*Npad;
    ALIGN64
    ushort* WKf_h   = (ushort*)(ws + o); o += 40*4*64*8/2;
    ALIGN64
    ushort* WKf_l   = (ushort*)(ws + o); o += 40*4*64*8/2;
    ushort* vT16    = (ushort*)vbuf;                     // dead after mega1

    float* out = (float*)d_out;
    float* A   = out + (size_t)N*ND;

    int tail = Npad - N;
    int zwork = 8*Npad + (128+256)*tail;
    int zb = (zwork + 4 + 255)/256;
    int egb = Npad/64;
    k_prep<<<dim3(64 + zb + egb), dim3(256), 0, stream>>>(
        Wq, Wk, Wv, proj, bq, bk, Wt_h, Wt_l, bd, kpT, vT16, mxk_u,
        gum, egT, zwork, zb, N, Npad);
    k_qkv<<<dim3((N+31)/32), dim3(256), 0, stream>>>(z, Wt_h, Wt_l, bq, bk, bv, bd,
                                                     qp, qpe, dd_k, diag_k, vT16, N, Npad);
    {
        size_t len = (size_t)N*NM;
        int mchunks = (int)((len + 8191)/8192);
        k_maxred<<<dim3(mchunks, 4), dim3(256), 0, stream>>>(dd_k, mxk_u, N);
    }
    k_kp<<<dim3(nkb), dim3(256), 0, stream>>>(dd_k, diag_k, mxk_u, kpe, kpT, kp_part, N, Npad);
    k_mid<<<dim3(120), dim3(256), 0, stream>>>(kp_part, kp_sum, nkb);
    int denb = (N+63)/64;
    k_mega1<<<dim3(704 + denb), dim3(256), 0, stream>>>(
        kpT, egT, vT16, kvs_part, kg_part, qp, kp_sum, qpe, N, Npad);
    k_red<<<dim3(305), dim3(256), 0, stream>>>(kvs_part, kvs, kg_part, kg_sum);
    k_wkprep<<<dim3(40), dim3(256), 0, stream>>>(kvs, Wo, WKf_h, WKf_l);
    {
        int zoB = (N+63)/64;
        int edgeB = (E+63)/64;
        int total = zoB + edgeB;
        int stride = (total + zoB - 1)/zoB;
        k_zoedge<<<dim3(total), dim3(256), 0, stream>>>(qp, WKf_h, WKf_l,
                                                        kg_sum, Wob, qpe, kpe,
                                                        ei, out, A, zoB, stride, N, E);
    }
}

// Round 19
// 403.927 us; speedup vs baseline: 1.0264x; 1.0264x over previous
//
#include <hip/hip_runtime.h>
#include <math.h>

#define NH 4
#define ND 64
#define NC 128
#define NHD 256
#define NM 30
#define NK 10
#define EPSF 1e-6f
#define RATIO 0.18257418583505536f    // 1/sqrt(30)
#define QKSCALE 0.7071067811865476f   // inv_sqrt_tau(=2) * 64^{-1/4}(=0.353553)
#define NSEG 48                       // kvs2 n-segments
#define NSEG2 128                     // kg_sum partial segments

typedef float f32x4 __attribute__((ext_vector_type(4)));
typedef short s16x8 __attribute__((ext_vector_type(8)));

__device__ __forceinline__ unsigned f2ord(float f){ unsigned b=__float_as_uint(f); return (b&0x80000000u)?~b:(b|0x80000000u); }
__device__ __forceinline__ float ord2f(unsigned u){ return __uint_as_float((u&0x80000000u)?(u&0x7fffffffu):~u); }
// round-to-nearest-even f32 -> bf16 (finite values)
__device__ __forceinline__ ushort f2bf(float f){ unsigned b=__float_as_uint(f); return (ushort)((b + 0x7fffu + ((b>>16)&1u))>>16); }
__device__ __forceinline__ float bf2f(ushort u){ return __uint_as_float(((unsigned)u)<<16); }
// split f32 -> bf16 hi + bf16 lo (hi+lo ~= p to 2^-17 rel)
__device__ __forceinline__ void bfsplit(float p, unsigned& hi, unsigned& lo){
    unsigned pb = __float_as_uint(p);
    unsigned t  = pb + 0x8000u;
    unsigned hf = t & 0xffff0000u;
    hi = t >> 16;
    lo = __float_as_uint(p - __uint_as_float(hf)) >> 16;
}

// ---------------------------------------------------------------------------
// K-prep (merged): blocks [0,48) = W q|k|v panel; [48,64) = dd-folded panel;
// [64,64+zb) = zero-fill pads; tail = init mxk_u.
// ---------------------------------------------------------------------------
__global__ __launch_bounds__(256) void k_prep(const float* __restrict__ Wq,
    const float* __restrict__ Wk, const float* __restrict__ Wv,
    const float* __restrict__ proj, const float* __restrict__ bq,
    const float* __restrict__ bk, ushort* __restrict__ Wt_h,
    ushort* __restrict__ Wt_l, float* __restrict__ bd, float* __restrict__ kpT,
    ushort* __restrict__ vT16, unsigned* __restrict__ mxk_u,
    int zwork, int N, int Npad)
{
    __shared__ float wd[16*129];
    int b = blockIdx.x;
    int tid = threadIdx.x;
    if (b < 48){
        int idx = b*256 + tid;
        int lane = idx & 63, ks = (idx>>6)&3, tile = idx>>8;
        int c = tile*16 + (lane&15);
        int k0 = ks*32 + (lane>>4)*8;
        const float* W; int cc;
        if (c < 256)      { W = Wq; cc = c; }
        else if (c < 512) { W = Wk; cc = c-256; }
        else              { W = Wv; cc = c-512; }
        #pragma unroll
        for (int j=0;j<8;j++){
            float w = W[(size_t)(k0+j)*NHD + cc];
            ushort h = f2bf(w);
            Wt_h[(size_t)idx*8+j] = h;
            Wt_l[(size_t)idx*8+j] = f2bf(w - bf2f(h));
        }
    } else if (b < 64){
        int dt = b - 48;
        int cl = tid & 15, rc = tid >> 4;
        int cd = dt*16 + cl;
        int isq = (cd < 128);
        int hm = cd & 127;
        int valid = (hm < 120);
        int hh = valid ? hm/30 : 0, m = valid ? hm%30 : 0;
        const float* W = isq ? Wq : Wk;
        const float* prow = proj + (size_t)m*ND;
        #pragma unroll
        for (int rr=0; rr<8; rr++){
            int row = rc*8 + rr;
            float s = 0.f;
            if (valid){
                const float* wr = W + (size_t)row*NHD + hh*64;
                for (int d=0; d<64; d++) s = fmaf(wr[d], prow[d], s);
                s *= QKSCALE;
            }
            wd[cl*129 + row] = s;
        }
        if (tid < 16){
            int cd2 = dt*16 + tid;
            int hm2 = cd2 & 127;
            float s = 0.f;
            if (hm2 < 120){
                int hh2 = hm2/30, m2 = hm2%30;
                const float* bvec = (cd2 < 128) ? bq : bk;
                const float* pr2 = proj + (size_t)m2*ND;
                for (int d=0; d<64; d++) s = fmaf(bvec[hh2*64+d], pr2[d], s);
                s *= QKSCALE;
            }
            bd[cd2] = s;
        }
        __syncthreads();
        int ks = tid >> 6, lane = tid & 63;
        int colL = lane & 15, k0 = ks*32 + (lane>>4)*8;
        unsigned hi[8], lo[8];
        #pragma unroll
        for (int j=0;j<8;j++){
            float v = wd[colL*129 + k0 + j];
            bfsplit(v, hi[j], lo[j]);
        }
        uint4 ph, pl;
        ph.x=hi[0]|(hi[1]<<16); ph.y=hi[2]|(hi[3]<<16); ph.z=hi[4]|(hi[5]<<16); ph.w=hi[6]|(hi[7]<<16);
        pl.x=lo[0]|(lo[1]<<16); pl.y=lo[2]|(lo[3]<<16); pl.z=lo[4]|(lo[5]<<16); pl.w=lo[6]|(lo[7]<<16);
        size_t off = ((size_t)(48+dt)*4 + ks)*64 + lane;
        ((uint4*)Wt_h)[off] = ph;
        ((uint4*)Wt_l)[off] = pl;
    } else {
        int idx = (b-64)*256 + tid;
        int tail = Npad - N;
        int w1 = 8*Npad, w2 = 128*tail, w3 = 256*tail;
        if (idx < w1){
            int r = idx / Npad, c = idx % Npad;
            int hh = r>>1, m = 30 + (r&1);
            kpT[((size_t)(hh*32+m))*Npad + c] = 0.f;
        } else if (idx < w1+w2){
            int j = idx - w1; int r = j / tail, c = N + j % tail;
            kpT[(size_t)r*Npad + c] = 0.f;
        } else if (idx < w1+w2+w3){
            int j = idx - w1 - w2; int r = j / tail, c = N + j % tail;
            vT16[(size_t)r*Npad + c] = 0;
        } else if (idx >= zwork && idx < zwork + 4){
            mxk_u[idx - zwork] = 0u;
        }
    }
}

// ---------------------------------------------------------------------------
// K1: single MFMA pass over 64 col-tiles (q|k|v|dd).  FROZEN (120us, 84 VGPR).
// ---------------------------------------------------------------------------
__global__ __launch_bounds__(256) void k_qkv(
    const float* __restrict__ z,
    const ushort* __restrict__ Wt_h, const ushort* __restrict__ Wt_l,
    const float* __restrict__ bq, const float* __restrict__ bk,
    const float* __restrict__ bv, const float* __restrict__ bd,
    float* __restrict__ qp, ushort* __restrict__ qpe,
    float* __restrict__ dd_k, float* __restrict__ diag_k,
    ushort* __restrict__ vT16, int N, int Npad)
{
    __shared__ float pq[32*132];
    __shared__ float diagq[32*4];
    __shared__ float mxs[32*4];
    int tid = threadIdx.x;
    int n0 = blockIdx.x * 32;
    int w = tid >> 6, lane = tid & 63;
    int l15 = lane & 15, kgrp = lane >> 4;

    s16x8 ah[2][4], al[2][4];
    #pragma unroll
    for (int g=0; g<2; g++){
        int nn = n0 + g*16 + l15; if (nn > N-1) nn = N-1;
        const float* zrow = z + (size_t)nn*NC;
        #pragma unroll
        for (int ks=0;ks<4;ks++){
            f32x4 f0 = *(const f32x4*)(zrow + ks*32 + kgrp*8);
            f32x4 f1 = *(const f32x4*)(zrow + ks*32 + kgrp*8 + 4);
            #pragma unroll
            for (int j=0;j<4;j++){
                float v0 = f0[j]; ushort h0 = f2bf(v0);
                ah[g][ks][j]   = (short)h0; al[g][ks][j]   = (short)f2bf(v0 - bf2f(h0));
                float v1 = f1[j]; ushort h1 = f2bf(v1);
                ah[g][ks][4+j] = (short)h1; al[g][ks][4+j] = (short)f2bf(v1 - bf2f(h1));
            }
        }
    }

    float sq0[4] = {0.f,0.f,0.f,0.f}, sq1[4] = {0.f,0.f,0.f,0.f};
    const uint4* WH = (const uint4*)Wt_h;
    const uint4* WL = (const uint4*)Wt_l;

    for (int nt=0; nt<16; nt++){
        int tile = w*16 + nt;
        f32x4 acc0 = {0.f,0.f,0.f,0.f}, acc1 = {0.f,0.f,0.f,0.f};
        #pragma unroll
        for (int ks=0;ks<4;ks++){
            uint4 bhu = WH[(size_t)(tile*4+ks)*64 + lane];
            uint4 blu = WL[(size_t)(tile*4+ks)*64 + lane];
            s16x8 bh = __builtin_bit_cast(s16x8, bhu);
            s16x8 bl = __builtin_bit_cast(s16x8, blu);
            acc0 = __builtin_amdgcn_mfma_f32_16x16x32_bf16(ah[0][ks], bl, acc0, 0,0,0);
            acc0 = __builtin_amdgcn_mfma_f32_16x16x32_bf16(al[0][ks], bh, acc0, 0,0,0);
            acc0 = __builtin_amdgcn_mfma_f32_16x16x32_bf16(ah[0][ks], bh, acc0, 0,0,0);
            acc1 = __builtin_amdgcn_mfma_f32_16x16x32_bf16(ah[1][ks], bl, acc1, 0,0,0);
            acc1 = __builtin_amdgcn_mfma_f32_16x16x32_bf16(al[1][ks], bh, acc1, 0,0,0);
            acc1 = __builtin_amdgcn_mfma_f32_16x16x32_bf16(ah[1][ks], bh, acc1, 0,0,0);
        }
        int c = tile*16 + l15;
        if (c < 512){
            int ccc = c & 255;
            float bias = (c < 256) ? bq[ccc] : bk[ccc];
            #pragma unroll
            for (int i=0;i<4;i++){
                float x0 = (acc0[i]+bias)*QKSCALE; sq0[i] = fmaf(x0,x0,sq0[i]);
                float x1 = (acc1[i]+bias)*QKSCALE; sq1[i] = fmaf(x1,x1,sq1[i]);
            }
            if ((nt&3)==3){
                int hh = nt>>2;
                #pragma unroll
                for (int i=0;i<4;i++){
                    float s0 = sq0[i], s1 = sq1[i];
                    s0 += __shfl_xor(s0,1); s0 += __shfl_xor(s0,2);
                    s0 += __shfl_xor(s0,4); s0 += __shfl_xor(s0,8);
                    s1 += __shfl_xor(s1,1); s1 += __shfl_xor(s1,2);
                    s1 += __shfl_xor(s1,4); s1 += __shfl_xor(s1,8);
                    if (l15==0){
                        int nd0 = kgrp*4+i, nd1 = 16+kgrp*4+i;
                        if (w==0){ diagq[nd0*4+hh] = 0.5f*s0; diagq[nd1*4+hh] = 0.5f*s1; }
                        else {
                            int na = n0+nd0, nb2 = n0+nd1;
                            if (na < N) diag_k[(size_t)na*4+hh] = 0.5f*s0;
                            if (nb2 < N) diag_k[(size_t)nb2*4+hh] = 0.5f*s1;
                        }
                    }
                    sq0[i]=0.f; sq1[i]=0.f;
                }
            }
        } else if (c < 768){
            int cv = c - 512;
            float bias = bv[cv];
            {
                ushort t0=f2bf(acc0[0]+bias), t1=f2bf(acc0[1]+bias);
                ushort t2=f2bf(acc0[2]+bias), t3=f2bf(acc0[3]+bias);
                int nb = n0 + kgrp*4;
                ushort* dst = &vT16[(size_t)cv*Npad + nb];
                if (nb+4 <= N){ uint2 pk; pk.x=(unsigned)t0|((unsigned)t1<<16); pk.y=(unsigned)t2|((unsigned)t3<<16); *(uint2*)dst=pk; }
                else { if(nb<N)dst[0]=t0; if(nb+1<N)dst[1]=t1; if(nb+2<N)dst[2]=t2; if(nb+3<N)dst[3]=t3; }
            }
            {
                ushort t0=f2bf(acc1[0]+bias), t1=f2bf(acc1[1]+bias);
                ushort t2=f2bf(acc1[2]+bias), t3=f2bf(acc1[3]+bias);
                int nb = n0 + 16 + kgrp*4;
                ushort* dst = &vT16[(size_t)cv*Npad + nb];
                if (nb+4 <= N){ uint2 pk; pk.x=(unsigned)t0|((unsigned)t1<<16); pk.y=(unsigned)t2|((unsigned)t3<<16); *(uint2*)dst=pk; }
                else { if(nb<N)dst[0]=t0; if(nb+1<N)dst[1]=t1; if(nb+2<N)dst[2]=t2; if(nb+3<N)dst[3]=t3; }
            }
        } else {
            int cd = c - 768;
            float bias = bd[cd];
            if (cd < 128){
                #pragma unroll
                for (int i=0;i<4;i++){
                    pq[(kgrp*4+i)*132 + cd]      = acc0[i]+bias;
                    pq[(16+kgrp*4+i)*132 + cd]   = acc1[i]+bias;
                }
            } else {
                int hm = cd - 128;
                if (hm < 120){
                    int hh = hm/30, m = hm%30;
                    size_t base = (size_t)hh*N*NM;
                    #pragma unroll
                    for (int i=0;i<4;i++){
                        int na = n0+kgrp*4+i, nb2 = n0+16+kgrp*4+i;
                        if (na < N)  dd_k[base + (size_t)na*NM + m]  = acc0[i]+bias;
                        if (nb2 < N) dd_k[base + (size_t)nb2*NM + m] = acc1[i]+bias;
                    }
                }
            }
        }
    }
    __syncthreads();

    if (tid < 128){
        int node = tid>>2, hh = tid&3;
        const float* pr = &pq[node*132 + hh*30];
        float mx = -3.0e38f;
        #pragma unroll
        for (int m=0;m<NM;m++) mx = fmaxf(mx, pr[m]);
        mxs[tid] = mx;
    }
    __syncthreads();

    for (int idx = tid; idx < 32*120; idx += 256){
        int node = idx/120, hm = idx%120;
        int n = n0 + node;
        if (n >= N) continue;
        int hh = hm/30;
        float val = RATIO * (__expf(pq[node*132+hm] - diagq[node*4+hh] - mxs[node*4+hh]) + EPSF);
        qp[(size_t)n*120 + hm] = val;
        qpe[(size_t)n*128 + hm] = f2bf(val);
    }
}

// ---------------------------------------------------------------------------
// K1.5: global max of dd_k per head — 32KB chunk/block, float4, 4 chains.
// ---------------------------------------------------------------------------
__global__ __launch_bounds__(256) void k_maxred(const float* __restrict__ dd_k,
                                                unsigned* __restrict__ mxk_u, int N)
{
    const int CH = 8192;
    int hh = blockIdx.y;
    size_t len = (size_t)N*NM;
    size_t base = (size_t)hh*len;
    size_t lo = (size_t)blockIdx.x*CH;
    size_t hi = lo + CH; if (hi > len) hi = len;
    float m0=-3.0e38f, m1=-3.0e38f, m2=-3.0e38f, m3=-3.0e38f;
    size_t j = lo + (size_t)threadIdx.x*4;
    for (; j + 4 <= hi; j += 1024){
        float4 v = *(const float4*)(dd_k + base + j);
        m0 = fmaxf(m0, v.x); m1 = fmaxf(m1, v.y);
        m2 = fmaxf(m2, v.z); m3 = fmaxf(m3, v.w);
    }
    if (j < hi){
        for (size_t t = j; t < hi; ++t) m0 = fmaxf(m0, dd_k[base + t]);
    }
    float mx = fmaxf(fmaxf(m0, m1), fmaxf(m2, m3));
    for (int o=32;o>0;o>>=1) mx = fmaxf(mx, __shfl_down(mx, o));
    __shared__ float wmax[4];
    if ((threadIdx.x & 63) == 0) wmax[threadIdx.x >> 6] = mx;
    __syncthreads();
    if (threadIdx.x == 0){
        mx = fmaxf(fmaxf(wmax[0],wmax[1]), fmaxf(wmax[2],wmax[3]));
        atomicMax(&mxk_u[hh], f2ord(mx));
    }
}

// ---------------------------------------------------------------------------
// K2: kp features.  64 nodes/block; kpT writes coalesced via LDS transpose.
// ---------------------------------------------------------------------------
__global__ __launch_bounds__(256) void k_kp(const float* __restrict__ dd_k,
    const float* __restrict__ diag_k, const unsigned* __restrict__ mxk_u,
    ushort* __restrict__ kpe, float* __restrict__ kpT,
    float* __restrict__ kp_part, int N, int Npad)
{
    __shared__ float tbuf[120*67];
    __shared__ float psum[120];
    int tid = threadIdx.x;
    if (tid < 120) psum[tid] = 0.f;
    float mxk[NH];
    #pragma unroll
    for (int hh=0;hh<NH;hh++) mxk[hh] = ord2f(mxk_u[hh]);
    __syncthreads();
    int n0 = blockIdx.x * 64;
    for (int r = 0; r < 30; r++) {
        int idx = r*256 + tid;
        int nl = idx / 120, hm = idx % 120;
        int n = n0 + nl;
        float val = 0.f;
        if (n < N){
            int hh = hm/30, m = hm%30;
            val = RATIO * (__expf(dd_k[(size_t)hh*N*NM + (size_t)n*NM + m]
                                  - diag_k[(size_t)n*4+hh] - mxk[hh]) + EPSF);
            kpe[(size_t)n*128 + hm] = f2bf(val);
            atomicAdd(&psum[hm], val);
        }
        tbuf[hm*67 + nl] = val;
    }
    __syncthreads();
    for (int i = tid; i < 120*64; i += 256){
        int row = i>>6, cc = i&63;
        int hh = row/30, m = row%30;
        kpT[(size_t)(hh*32+m)*Npad + n0 + cc] = tbuf[row*67 + cc];
    }
    if (tid < 120) kp_part[blockIdx.x*120 + tid] = psum[tid];
}

// ---------------------------------------------------------------------------
// K-mid (merged): blocks [0,120) = kp_sum column reduce; rest = egT fill.
// ---------------------------------------------------------------------------
__global__ __launch_bounds__(256) void k_mid(const float* __restrict__ kp_part,
    float* __restrict__ kp_sum, int nblk,
    const float* __restrict__ gum, float* __restrict__ egT, int N, int Npad)
{
    __shared__ float ws_[4];
    int b = blockIdx.x;
    int tid = threadIdx.x;
    if (b < 120){
        float s = 0.f;
        for (int bb = tid; bb < nblk; bb += 256) s += kp_part[(size_t)bb*120 + b];
        for (int o=32;o>0;o>>=1) s += __shfl_down(s, o);
        if ((tid & 63) == 0) ws_[tid>>6] = s;
        __syncthreads();
        if (tid == 0) kp_sum[b] = ws_[0]+ws_[1]+ws_[2]+ws_[3];
    } else {
        int n0 = (b-120)*64;
        for (int i = tid; i < 64*40; i += 256){
            int nl = i / 40, hk = i % 40;
            int n = n0 + nl;
            if (n >= Npad) continue;
            float v = (n < N) ? __expf(gum[(size_t)n*40 + hk]) : 0.f;
            egT[(size_t)hk*Npad + n] = v;
        }
    }
}

// ---------------------------------------------------------------------------
// K-mega1 (fused): [0,192) kvs2 MFMA partials; [192,704) kg partials;
// [704,704+denb) den = qp . kp_sum -> qpe row tails.
// ---------------------------------------------------------------------------
__global__ __launch_bounds__(256,1) void k_mega1(const float* __restrict__ kpT,
    const float* __restrict__ egT, const ushort* __restrict__ vT16,
    float* __restrict__ part, float* __restrict__ kg_part,
    const float* __restrict__ qp, const float* __restrict__ kp_sum,
    ushort* __restrict__ qpe, int N, int Npad)
{
    __shared__ float kps_s[120];
    int b = blockIdx.x;
    int tid = threadIdx.x;
    if (b < 192){
        int seg = b % NSEG, hh = b / NSEG;
        int w = tid >> 6, lane = tid & 63;
        int l15 = lane & 15, lg = lane >> 4;
        int steps_total = Npad/32;
        int per = (steps_total + NSEG-1)/NSEG;
        int s0 = seg*per, s1 = min(steps_total, s0+per);

        const ushort* vbase = vT16 + (size_t)hh*64*Npad;
        const float* kpbase = kpT + (size_t)hh*32*Npad;
        const float* egbase = egT + (size_t)hh*10*Npad;

        f32x4 acc[5][4];
        #pragma unroll
        for (int mt=0;mt<5;mt++)
            #pragma unroll
            for (int nt=0;nt<4;nt++) acc[mt][nt] = (f32x4){0.f,0.f,0.f,0.f};

        for (int st = s0; st < s1; ++st){
            int n0 = st*32 + lg*8;
            s16x8 bf[4];
            #pragma unroll
            for (int nt=0;nt<4;nt++){
                uint4 u = *(const uint4*)(vbase + (size_t)(nt*16 + l15)*Npad + n0);
                bf[nt] = __builtin_bit_cast(s16x8, u);
            }
            #pragma unroll
            for (int mt=0;mt<5;mt++){
                int r = w*80 + mt*16 + l15;
                int m = r & 31, kk = r >> 5;
                const float* kprow = kpbase + (size_t)m*Npad;
                const float* egrow = egbase + (size_t)kk*Npad;
                f32x4 kp0 = *(const f32x4*)(kprow + n0);
                f32x4 kp1 = *(const f32x4*)(kprow + n0 + 4);
                f32x4 eg0 = *(const f32x4*)(egrow + n0);
                f32x4 eg1 = *(const f32x4*)(egrow + n0 + 4);
                f32x4 pr0 = kp0*eg0, pr1 = kp1*eg1;
                unsigned hi[8], lo[8];
                #pragma unroll
                for (int j=0;j<4;j++){
                    bfsplit(pr0[j], hi[j], lo[j]);
                    bfsplit(pr1[j], hi[4+j], lo[4+j]);
                }
                uint4 ahu, alu;
                ahu.x = hi[0]|(hi[1]<<16); ahu.y = hi[2]|(hi[3]<<16);
                ahu.z = hi[4]|(hi[5]<<16); ahu.w = hi[6]|(hi[7]<<16);
                alu.x = lo[0]|(lo[1]<<16); alu.y = lo[2]|(lo[3]<<16);
                alu.z = lo[4]|(lo[5]<<16); alu.w = lo[6]|(lo[7]<<16);
                s16x8 ah = __builtin_bit_cast(s16x8, ahu);
                s16x8 al = __builtin_bit_cast(s16x8, alu);
                #pragma unroll
                for (int nt=0;nt<4;nt++){
                    acc[mt][nt] = __builtin_amdgcn_mfma_f32_16x16x32_bf16(al, bf[nt], acc[mt][nt], 0,0,0);
                    acc[mt][nt] = __builtin_amdgcn_mfma_f32_16x16x32_bf16(ah, bf[nt], acc[mt][nt], 0,0,0);
                }
            }
        }
        float* dst = part + ((size_t)hh*NSEG + seg)*20480;
        #pragma unroll
        for (int mt=0;mt<5;mt++)
            #pragma unroll
            for (int nt=0;nt<4;nt++)
                #pragma unroll
                for (int i=0;i<4;i++){
                    int rr = w*80 + mt*16 + lg*4 + i;
                    dst[rr*64 + nt*16 + l15] = acc[mt][nt][i];
                }
    } else if (b < 704){
        int idx = b - 192;
        int s2 = idx & (NSEG2-1), hh = idx >> 7;
        int len = Npad / NSEG2;
        int n0 = s2*len;
        for (int t = tid; t < 320; t += 256){
            int kk = t >> 5, m = t & 31;
            float acc = 0.f;
            if (kk < NK && m < NM){
                const f32x4* kr = (const f32x4*)(kpT + ((size_t)(hh*32+m))*Npad + n0);
                const f32x4* er = (const f32x4*)(egT + ((size_t)(hh*10+kk))*Npad + n0);
                for (int i=0;i<len/4;i++){
                    f32x4 a = kr[i], bb = er[i];
                    acc = fmaf(a.x, bb.x, acc); acc = fmaf(a.y, bb.y, acc);
                    acc = fmaf(a.z, bb.z, acc); acc = fmaf(a.w, bb.w, acc);
                }
            }
            kg_part[((size_t)hh*NSEG2 + s2)*320 + t] = acc;
        }
    } else {
        // den blocks: 64 nodes each
        int n0 = (b - 704)*64;
        for (int i=tid;i<120;i+=256) kps_s[i] = kp_sum[i];
        __syncthreads();
        int nl = tid >> 2, h = tid & 3;
        int n = n0 + nl;
        if (n < N){
            const float* qrow = qp + (size_t)n*120 + h*30;
            float p = 0.f;
            #pragma unroll
            for (int m=0;m<30;m++) p = fmaf(qrow[m], kps_s[h*30+m], p);
            ((float*)qpe)[(size_t)n*64 + 60 + h] = p;
        }
    }
}

// ---------------------------------------------------------------------------
// K-red (merged): blocks [0,300) = kvs partial reduce; [300,305) = kg reduce.
// ---------------------------------------------------------------------------
__global__ __launch_bounds__(256) void k_red(const float* __restrict__ part,
    float* __restrict__ kvs, const float* __restrict__ kg_part,
    float* __restrict__ kg_sum)
{
    int b = blockIdx.x, tid = threadIdx.x;
    if (b < 300){
        int o = b*256 + tid;   // 76800 = 4h*10k*30m*64d
        if (o >= 76800) return;
        int hh = o / 19200, r = o % 19200;
        int km = r >> 6, d = r & 63;
        int kk = km / 30, m = km % 30;
        size_t base = (size_t)hh*NSEG*20480 + (size_t)(kk*32+m)*64 + d;
        float s = 0.f;
        for (int sg=0; sg<NSEG; sg++) s += part[base + (size_t)sg*20480];
        kvs[o] = s;
    } else {
        int o = (b-300)*256 + tid;   // 1200
        if (o >= 1200) return;
        int hh = o / 300, r = o % 300;
        int kk = r / 30, m = r % 30;
        float s = 0.f;
        for (int i=0;i<NSEG2;i++) s += kg_part[((size_t)hh*NSEG2 + i)*320 + kk*32 + m];
        kg_sum[o] = s;
    }
}

// ---------------------------------------------------------------------------
// K4: WK panels = kvs @ Wo folded, in MFMA B-frag layout, bf16 hi/lo.
// ---------------------------------------------------------------------------
__global__ __launch_bounds__(256) void k_wkprep(const float* __restrict__ kvs,
    const float* __restrict__ Wo, ushort* __restrict__ WKf_h, ushort* __restrict__ WKf_l)
{
    __shared__ float kv_s[30*65];
    __shared__ float wo_s[64*64];
    __shared__ float wks[32*64];
    int ks = blockIdx.x;
    int h = ks/10, kq = ks%10;
    int tid = threadIdx.x;
    for (int i=tid;i<1920;i+=256){ int m=i>>6, d=i&63; kv_s[m*65+d] = kvs[(size_t)h*19200 + (size_t)(kq*30)*64 + i]; }
    for (int i=tid;i<4096;i+=256) wo_s[i] = Wo[(size_t)h*64*64 + i];
    __syncthreads();
    int m = tid>>3, c0 = (tid&7)*8;
    float acc[8] = {0,0,0,0,0,0,0,0};
    if (m < 30){
        for (int d=0; d<64; d++){
            float kv = kv_s[m*65+d];
            const float* wr = &wo_s[d*64 + c0];
            #pragma unroll
            for (int j=0;j<8;j++) acc[j] = fmaf(kv, wr[j], acc[j]);
        }
    }
    #pragma unroll
    for (int j=0;j<8;j++) wks[m*64 + c0 + j] = acc[j];
    __syncthreads();
    int nt = tid>>6, lane = tid&63, l15 = lane&15, lg = lane>>4;
    unsigned hi[8], lo[8];
    #pragma unroll
    for (int jj=0;jj<8;jj++){
        float v = wks[(lg*8+jj)*64 + nt*16 + l15];
        bfsplit(v, hi[jj], lo[jj]);
    }
    uint4 ph, pl;
    ph.x = hi[0]|(hi[1]<<16); ph.y = hi[2]|(hi[3]<<16); ph.z = hi[4]|(hi[5]<<16); ph.w = hi[6]|(hi[7]<<16);
    pl.x = lo[0]|(lo[1]<<16); pl.y = lo[2]|(lo[3]<<16); pl.z = lo[4]|(lo[5]<<16); pl.w = lo[6]|(lo[7]<<16);
    size_t off = ((size_t)ks*4 + nt)*64 + lane;
    ((uint4*)WKf_h)[off] = ph;
    ((uint4*)WKf_l)[off] = pl;
}

// ---------------------------------------------------------------------------
// K-zoedge (fused): blocks [0, zoB) = zo MFMA output; [zoB, zoB+edgeB) = edge
// attention weights (overlaps zo's compute with the HBM-bound edge gather).
// ---------------------------------------------------------------------------
__global__ __launch_bounds__(256) void k_zoedge(const float* __restrict__ qp,
    const ushort* __restrict__ WKf_h, const ushort* __restrict__ WKf_l,
    const float* __restrict__ kg_sum, const float* __restrict__ Wob,
    const ushort* __restrict__ qpe, const ushort* __restrict__ kpe,
    const int* __restrict__ ei, float* __restrict__ out, float* __restrict__ A,
    int zoB, int N, int E)
{
    __shared__ float kg_s[1200];
    __shared__ uint4 bs[2][2][256];
    int tid = threadIdx.x;
    int b = blockIdx.x;
    if (b < zoB){
        int w = tid>>6, lane = tid&63, l15 = lane&15, lg = lane>>4;
        int n0 = b*64;
        int n = n0 + w*16 + l15;
        bool nv = (n < N);
        int nc = nv ? n : (N-1);

        for (int i=tid;i<1200;i+=256) kg_s[i] = kg_sum[i];
        {
            const uint4* sH = (const uint4*)WKf_h;
            const uint4* sL = (const uint4*)WKf_l;
            bs[0][0][tid] = sH[tid];
            bs[0][1][tid] = sL[tid];
        }

        float qA[4][8];
        const float* qrow = qp + (size_t)nc*120;
        #pragma unroll
        for (int h=0;h<4;h++)
          #pragma unroll
          for (int jj=0;jj<8;jj++){
            int m = lg*8+jj;
            qA[h][jj] = (m<30) ? qrow[h*30+m] : 0.f;
          }
        __syncthreads();

        f32x4 acc[4];
        #pragma unroll
        for (int nt=0;nt<4;nt++) acc[nt] = (f32x4){0.f,0.f,0.f,0.f};

        #pragma unroll
        for (int h=0;h<4;h++){
          for (int kq=0;kq<10;kq++){
            int ks = h*10+kq;
            int buf = ks&1;
            if (ks < 39){
                const uint4* sH = (const uint4*)WKf_h + (size_t)(ks+1)*256;
                const uint4* sL = (const uint4*)WKf_l + (size_t)(ks+1)*256;
                bs[buf^1][0][tid] = sH[tid];
                bs[buf^1][1][tid] = sL[tid];
            }
            float p = 0.f;
            #pragma unroll
            for (int jj=0;jj<8;jj++){
              int m = lg*8+jj;
              if (m<30) p = fmaf(qA[h][jj], kg_s[h*300 + kq*30 + m], p);
            }
            p += __shfl_xor(p,16);
            p += __shfl_xor(p,32);
            float sc = 0.1f / p;
            unsigned hi[8], lo[8];
            #pragma unroll
            for (int jj=0;jj<8;jj++) bfsplit(qA[h][jj]*sc, hi[jj], lo[jj]);
            uint4 ahu, alu;
            ahu.x = hi[0]|(hi[1]<<16); ahu.y = hi[2]|(hi[3]<<16);
            ahu.z = hi[4]|(hi[5]<<16); ahu.w = hi[6]|(hi[7]<<16);
            alu.x = lo[0]|(lo[1]<<16); alu.y = lo[2]|(lo[3]<<16);
            alu.z = lo[4]|(lo[5]<<16); alu.w = lo[6]|(lo[7]<<16);
            s16x8 ah = __builtin_bit_cast(s16x8, ahu);
            s16x8 al = __builtin_bit_cast(s16x8, alu);
            #pragma unroll
            for (int nt=0;nt<4;nt++){
                s16x8 bh = __builtin_bit_cast(s16x8, bs[buf][0][nt*64+lane]);
                s16x8 bl = __builtin_bit_cast(s16x8, bs[buf][1][nt*64+lane]);
                acc[nt] = __builtin_amdgcn_mfma_f32_16x16x32_bf16(ah, bl, acc[nt], 0,0,0);
                acc[nt] = __builtin_amdgcn_mfma_f32_16x16x32_bf16(al, bh, acc[nt], 0,0,0);
                acc[nt] = __builtin_amdgcn_mfma_f32_16x16x32_bf16(ah, bh, acc[nt], 0,0,0);
            }
            __syncthreads();
          }
        }

        #pragma unroll
        for (int nt=0;nt<4;nt++){
            float bias = Wob[nt*16 + l15];
            #pragma unroll
            for (int i=0;i<4;i++){
                int node = n0 + w*16 + lg*4 + i;
                if (node < N) out[(size_t)node*64 + nt*16 + l15] = acc[nt][i] + bias;
            }
        }
    } else {
        int e = (b - zoB)*64 + (tid>>2);
        int sub = tid & 3;
        if (e >= E) return;
        int s = ei[e], t = ei[(size_t)E + e];
        float dnv = ((const float*)(qpe + (size_t)t*128))[60 + sub];   // issue early
        const uint4* rq = (const uint4*)(qpe + (size_t)t*128) + sub*4;
        const uint4* rk = (const uint4*)(kpe + (size_t)s*128) + sub*4;
        float numA = 0.f, numB = 0.f;
        int bndw = 15 - sub;   // u32-index boundary within quarter
        #define PROC(au,bu,wi) { \
            float a0=__uint_as_float((au)<<16),        b0=__uint_as_float((bu)<<16); \
            float a1=__uint_as_float((au)&0xffff0000u),b1=__uint_as_float((bu)&0xffff0000u); \
            float p = fmaf(a0,b0, a1*b1); \
            if ((wi) < bndw) numA += p; else if (sub < 3) numB += p; }
        #pragma unroll
        for (int j=0;j<4;j++){
            uint4 a = rq[j], bb = rk[j];
            PROC(a.x, bb.x, j*4+0)
            PROC(a.y, bb.y, j*4+1)
            PROC(a.z, bb.z, j*4+2)
            PROC(a.w, bb.w, j*4+3)
        }
        #undef PROC
        int lane = tid & 63;
        float nbIn = __shfl(numB, (lane > 0) ? (lane-1) : 0);
        float num = numA + ((sub > 0) ? nbIn : 0.f);
        A[(size_t)e*4 + sub] = num / dnv;
    }
}

// ---------------------------------------------------------------------------
extern "C" void kernel_launch(void* const* d_in, const int* in_sizes, int n_in,
                              void* d_out, int out_size, void* d_ws, size_t ws_size,
                              hipStream_t stream)
{
    const float* z    = (const float*)d_in[0];
    const int*   ei   = (const int*)d_in[1];
    const float* gum  = (const float*)d_in[2];
    const float* proj = (const float*)d_in[3];
    const float* Wq   = (const float*)d_in[4];
    const float* bq   = (const float*)d_in[5];
    const float* Wk   = (const float*)d_in[6];
    const float* bk   = (const float*)d_in[7];
    const float* Wv   = (const float*)d_in[8];
    const float* bv   = (const float*)d_in[9];
    const float* Wo   = (const float*)d_in[10];
    const float* Wob  = (const float*)d_in[11];
    int N = in_sizes[0] / NC;
    int E = in_sizes[1] / 2;
    int Npad = (N + 511) & ~511;

    float* ws = (float*)d_ws;
    size_t o = 0;
    #define ALIGN64 o = (o + 63) & ~(size_t)63;
    float* qp       = ws + o; o += (size_t)N*120;
    ALIGN64
    float* vbuf     = ws + o; o += (size_t)N*NHD;
    ALIGN64
    float* dd_k     = ws + o; o += (size_t)NH*N*NM;      // kvs_part aliases (after kp)
    float* kvs_part = dd_k;
    ALIGN64
    float* egT      = ws + o; o += (size_t)40*Npad;      // separate (filled in mid)
    ALIGN64
    float* diag_k   = ws + o; o += (size_t)N*4;
    unsigned* mxk_u = (unsigned*)(ws + o); o += 4;
    ALIGN64
    int nkb = (N+63)/64;
    float* kp_part  = ws + o; o += (size_t)nkb*120;
    float* kp_sum   = ws + o; o += 120;
    ALIGN64
    float* kg_part  = ws + o; o += (size_t)NH*NSEG2*320;
    float* kvs      = ws + o; o += 76800;
    float* kg_sum   = ws + o; o += 1200;
    ALIGN64
    ushort* qpe     = (ushort*)(ws + o); o += (size_t)N*64;
    ALIGN64
    ushort* kpe     = (ushort*)(ws + o); o += (size_t)N*64;
    ALIGN64
    ushort* Wt_h    = (ushort*)(ws + o); o += 64*4*64*8/2;
    ALIGN64
    ushort* Wt_l    = (ushort*)(ws + o); o += 64*4*64*8/2;
    ALIGN64
    float* bd       = ws + o; o += 256;
    ALIGN64
    float* kpT      = ws + o; o += (size_t)128*Npad;
    ALIGN64
    ushort* WKf_h   = (ushort*)(ws + o); o += 40*4*64*8/2;
    ALIGN64
    ushort* WKf_l   = (ushort*)(ws + o); o += 40*4*64*8/2;
    ushort* vT16    = (ushort*)vbuf;                     // dead after mega1

    float* out = (float*)d_out;
    float* A   = out + (size_t)N*ND;

    int tail = Npad - N;
    int zwork = 8*Npad + (128+256)*tail;
    int zb = (zwork + 4 + 255)/256;
    k_prep<<<dim3(64 + zb), dim3(256), 0, stream>>>(Wq, Wk, Wv, proj, bq, bk,
                                                    Wt_h, Wt_l, bd, kpT, vT16,
                                                    mxk_u, zwork, N, Npad);
    k_qkv<<<dim3((N+31)/32), dim3(256), 0, stream>>>(z, Wt_h, Wt_l, bq, bk, bv, bd,
                                                     qp, qpe, dd_k, diag_k, vT16, N, Npad);
    {
        size_t len = (size_t)N*NM;
        int mchunks = (int)((len + 8191)/8192);
        k_maxred<<<dim3(mchunks, 4), dim3(256), 0, stream>>>(dd_k, mxk_u, N);
    }
    k_kp<<<dim3(nkb), dim3(256), 0, stream>>>(dd_k, diag_k, mxk_u, kpe, kpT, kp_part, N, Npad);
    k_mid<<<dim3(120 + Npad/64), dim3(256), 0, stream>>>(kp_part, kp_sum, nkb,
                                                         gum, egT, N, Npad);
    int denb = (N+63)/64;
    k_mega1<<<dim3(704 + denb), dim3(256), 0, stream>>>(kpT, egT, vT16, kvs_part,
                                                        kg_part, qp, kp_sum, qpe,
                                                        N, Npad);
    k_red<<<dim3(305), dim3(256), 0, stream>>>(kvs_part, kvs, kg_part, kg_sum);
    k_wkprep<<<dim3(40), dim3(256), 0, stream>>>(kvs, Wo, WKf_h, WKf_l);
    {
        int zoB = (N+63)/64;
        int edgeB = (E+63)/64;
        k_zoedge<<<dim3(zoB + edgeB), dim3(256), 0, stream>>>(qp, WKf_h, WKf_l,
                                                              kg_sum, Wob, qpe, kpe,
                                                              ei, out, A, zoB, N, E);
    }
}